// Round 5
// baseline (72.729 us; speedup 1.0000x reference)
//
#include <hip/hip_runtime.h>

#define NEG_SLOPE 0.2f
#define EPS 1e-6f

// x: [B=4, C=64, V=3, N=32768] f32, W: [64,64] f32, out like x
// d[o,v,n] = sum_i W[o,i]*x[i,v,n]; out = dot>=0 ? x : x - 0.8*(dot/(dnsq+eps))*d
// bf16 MFMA, hi/lo 3-product split. Persistent blocks: 4 n-tiles each,
// register prefetch of next tile overlaps compute of current.

#define C_CH 64
#define V_DIM 3
#define N_FULL 32768
#define NT 32
#define THREADS 256
#define TPB 4   // tiles per block

typedef __attribute__((ext_vector_type(8))) short bf16x8;
typedef __attribute__((ext_vector_type(4))) float f32x4;

__device__ __forceinline__ ushort f2bf(float f) {
    union { float f; unsigned u; } v; v.f = f;
    unsigned r = v.u + 0x7FFFu + ((v.u >> 16) & 1u);  // RNE
    return (ushort)(r >> 16);
}
__device__ __forceinline__ float bf2f(ushort s) {
    union { unsigned u; float f; } v; v.u = ((unsigned)s) << 16; return v.f;
}
// pack f32 -> (hi bf16 | lo bf16) in 5 VALU: round-half-up hi, truncated lo
__device__ __forceinline__ unsigned pack_hl(float x) {
    union { float f; unsigned u; } a; a.f = x;
    unsigned uh = (a.u + 0x8000u) & 0xffff0000u;
    union { unsigned u; float f; } hb; hb.u = uh;
    union { float f; unsigned u; } rb; rb.f = x - hb.f;
    return uh | (rb.u >> 16);
}
__device__ __forceinline__ float u2f(unsigned u) {
    union { unsigned u; float f; } v; v.u = u; return v.f;
}

// ---- pre-kernel: split W fp32 -> Whi/Wlo bf16 (8 KB each), RNE both
__global__ void w_split_kernel(const float* __restrict__ W,
                               ushort* __restrict__ whi, ushort* __restrict__ wlo) {
    int i = blockIdx.x * 256 + threadIdx.x;
    if (i < C_CH * C_CH) {
        float w = W[i];
        ushort h = f2bf(w);
        whi[i] = h;
        wlo[i] = f2bf(w - bf2f(h));
    }
}

__device__ __forceinline__ int swz(int row) { return ((row >> 3) & 7) << 2; }

template<bool USE_WS>
__global__ __launch_bounds__(THREADS, 4)
void vn_mfma32(const float* __restrict__ x,
               const float* __restrict__ Wf,
               const ushort* __restrict__ whi, const ushort* __restrict__ wlo,
               float* __restrict__ out) {
    __shared__ unsigned xs[C_CH * V_DIM][NT];  // packed (hi<<16)|lo, 24 KB

    const int t    = threadIdx.x;
    const int lane = t & 63;
    const int w    = t >> 6;
    const int wo   = w >> 1;   // o-half -> 32 rows
    const int wn   = w & 1;    // n-half -> 16 cols
    const int l4   = lane & 15;
    const int hi   = lane >> 4;

    // staging geometry (fixed per thread)
    const int srow = t >> 3;          // 0..31  base row of this thread's slots
    const int sc4  = (t & 7) << 2;    // dword col

    // ---- A fragments once per block: Ah/Al[m][kh]
    bf16x8 Ah[2][2], Al[2][2];
    if (USE_WS) {
        #pragma unroll
        for (int m = 0; m < 2; ++m)
            #pragma unroll
            for (int kh = 0; kh < 2; ++kh) {
                size_t off = (size_t)(wo * 32 + m * 16 + l4) * C_CH + kh * 32 + hi * 8;
                Ah[m][kh] = *(const bf16x8*)(whi + off);
                Al[m][kh] = *(const bf16x8*)(wlo + off);
            }
    } else {
        #pragma unroll
        for (int m = 0; m < 2; ++m)
            #pragma unroll
            for (int kh = 0; kh < 2; ++kh) {
                const float* wp = Wf + (size_t)(wo * 32 + m * 16 + l4) * C_CH + kh * 32 + hi * 8;
                float4 wa = *(const float4*)wp;
                float4 wb = *(const float4*)(wp + 4);
                float wf[8] = {wa.x, wa.y, wa.z, wa.w, wb.x, wb.y, wb.z, wb.w};
                bf16x8 h, l;
                #pragma unroll
                for (int j = 0; j < 8; ++j) {
                    ushort hb = f2bf(wf[j]);
                    h[j] = (short)hb;
                    l[j] = (short)f2bf(wf[j] - bf2f(hb));
                }
                Ah[m][kh] = h; Al[m][kh] = l;
            }
    }

    // ---- prefetch tile 0
    int tile = blockIdx.x * TPB;
    const float* xb = x + (size_t)(tile >> 10) * (C_CH * V_DIM * N_FULL)
                        + ((tile & 1023) << 5);
    float4 pre[6];
    #pragma unroll
    for (int it = 0; it < 6; ++it)
        pre[it] = *(const float4*)(xb + (size_t)(srow + it * 32) * N_FULL + sc4);

    #pragma unroll
    for (int tt = 0; tt < TPB; ++tt) {
        if (tt) __syncthreads();   // previous tile's LDS reads done

        // ---- convert prefetched regs -> packed LDS
        #pragma unroll
        for (int it = 0; it < 6; ++it) {
            int row = srow + it * 32;
            float vf[4] = {pre[it].x, pre[it].y, pre[it].z, pre[it].w};
            unsigned p[4];
            #pragma unroll
            for (int q = 0; q < 4; ++q) p[q] = pack_hl(vf[q]);
            *(uint4*)&xs[row][sc4 ^ swz(row)] = *(const uint4*)p;
        }

        // ---- issue next tile's loads (latency hides under compute below)
        if (tt + 1 < TPB) {
            int tn = tile + 1;
            const float* xbn = x + (size_t)(tn >> 10) * (C_CH * V_DIM * N_FULL)
                                 + ((tn & 1023) << 5);
            #pragma unroll
            for (int it = 0; it < 6; ++it)
                pre[it] = *(const float4*)(xbn + (size_t)(srow + it * 32) * N_FULL + sc4);
        }
        __syncthreads();

        // ---- MFMA: B-frag unpack from packed LDS, 3-product hi/lo
        f32x4 acc[2][3];
        #pragma unroll
        for (int m = 0; m < 2; ++m)
            #pragma unroll
            for (int v = 0; v < 3; ++v)
                acc[m][v] = (f32x4){0.f, 0.f, 0.f, 0.f};

        #pragma unroll
        for (int v = 0; v < 3; ++v) {
            #pragma unroll
            for (int kh = 0; kh < 2; ++kh) {
                bf16x8 bh, bl;
                #pragma unroll
                for (int j = 0; j < 8; ++j) {
                    int row = (kh * 32 + hi * 8 + j) * V_DIM + v;
                    unsigned p = xs[row][(wn * 16 + l4) ^ swz(row)];
                    bh[j] = (short)(p >> 16);
                    bl[j] = (short)(p & 0xffffu);
                }
                #pragma unroll
                for (int m = 0; m < 2; ++m) {
                    acc[m][v] = __builtin_amdgcn_mfma_f32_16x16x32_bf16(Ah[m][kh], bh, acc[m][v], 0, 0, 0);
                    acc[m][v] = __builtin_amdgcn_mfma_f32_16x16x32_bf16(Ah[m][kh], bl, acc[m][v], 0, 0, 0);
                    acc[m][v] = __builtin_amdgcn_mfma_f32_16x16x32_bf16(Al[m][kh], bh, acc[m][v], 0, 0, 0);
                }
            }
        }

        // ---- epilogue: C/D col=l4 (n), row=hi*4+r (o within 16)
        const int n = wn * 16 + l4;
        float* ob = out + (size_t)(tile >> 10) * (C_CH * V_DIM * N_FULL)
                        + ((tile & 1023) << 5) + n;
        #pragma unroll
        for (int m = 0; m < 2; ++m) {
            #pragma unroll
            for (int r = 0; r < 4; ++r) {
                const int o = wo * 32 + m * 16 + hi * 4 + r;
                float xv[3], dv[3];
                #pragma unroll
                for (int v = 0; v < 3; ++v) {
                    int row = o * V_DIM + v;
                    unsigned p = xs[row][n ^ swz(row)];
                    xv[v] = u2f(p & 0xffff0000u) + u2f(p << 16);
                    dv[v] = acc[m][v][r];
                }
                float dot  = xv[0] * dv[0] + xv[1] * dv[1] + xv[2] * dv[2];
                float dnsq = dv[0] * dv[0] + dv[1] * dv[1] + dv[2] * dv[2];
                float f = (1.0f - NEG_SLOPE) * dot / (dnsq + EPS);
                float o0, o1, o2;
                if (dot >= 0.f) {
                    o0 = xv[0]; o1 = xv[1]; o2 = xv[2];
                } else {
                    o0 = xv[0] - f * dv[0]; o1 = xv[1] - f * dv[1]; o2 = xv[2] - f * dv[2];
                }
                float* op = ob + (size_t)o * (V_DIM * N_FULL);
                op[0 * N_FULL] = o0;
                op[1 * N_FULL] = o1;
                op[2 * N_FULL] = o2;
            }
        }

        ++tile;
    }
}

extern "C" void kernel_launch(void* const* d_in, const int* in_sizes, int n_in,
                              void* d_out, int out_size, void* d_ws, size_t ws_size,
                              hipStream_t stream) {
    const float* x = (const float*)d_in[0];
    const float* W = (const float*)d_in[1];
    float* out = (float*)d_out;

    const int B = 4;
    const int blocks = B * (N_FULL / NT) / TPB;  // 1024

    if (ws_size >= 2u * C_CH * C_CH * sizeof(ushort)) {
        ushort* whi = (ushort*)d_ws;
        ushort* wlo = whi + C_CH * C_CH;
        w_split_kernel<<<(C_CH * C_CH + 255) / 256, 256, 0, stream>>>(W, whi, wlo);
        vn_mfma32<true><<<blocks, THREADS, 0, stream>>>(x, W, whi, wlo, out);
    } else {
        vn_mfma32<false><<<blocks, THREADS, 0, stream>>>(x, W, nullptr, nullptr, out);
    }
}

// Round 6
// 44.742 us; speedup vs baseline: 1.6255x; 1.6255x over previous
//
#include <hip/hip_runtime.h>

#define NEG_SLOPE 0.2f
#define EPS 1e-6f

// x: [B=4, C=64, V=3, N=32768] f32, W: [64,64] f32, out like x
// d[o,v,n] = sum_i W[o,i]*x[i,v,n]; out = dot>=0 ? x : x - 0.8*(dot/(dnsq+eps))*d
// bf16 MFMA, hi/lo 3-product split. Single tile/block (R4 skeleton),
// LDS layout [v][i][n] + bank-half swizzle -> <=2-way (free),
// v_perm unpack, 6 blocks/CU.

#define C_CH 64
#define V_DIM 3
#define N_FULL 32768
#define NT 32
#define THREADS 256

typedef __attribute__((ext_vector_type(8))) short bf16x8;
typedef __attribute__((ext_vector_type(4))) float f32x4;

__device__ __forceinline__ ushort f2bf(float f) {
    union { float f; unsigned u; } v; v.f = f;
    unsigned r = v.u + 0x7FFFu + ((v.u >> 16) & 1u);  // RNE
    return (ushort)(r >> 16);
}
__device__ __forceinline__ float bf2f(ushort s) {
    union { unsigned u; float f; } v; v.u = ((unsigned)s) << 16; return v.f;
}
// pack f32 -> (hi bf16 | lo bf16): round-half-up hi, truncated lo
__device__ __forceinline__ unsigned pack_hl(float x) {
    union { float f; unsigned u; } a; a.f = x;
    unsigned uh = (a.u + 0x8000u) & 0xffff0000u;
    union { unsigned u; float f; } hb; hb.u = uh;
    union { float f; unsigned u; } rb; rb.f = x - hb.f;
    return uh | (rb.u >> 16);
}
__device__ __forceinline__ float u2f(unsigned u) {
    union { unsigned u; float f; } v; v.u = u; return v.f;
}

// ---- pre-kernel: split W fp32 -> Whi/Wlo bf16 (8 KB each), RNE both
__global__ void w_split_kernel(const float* __restrict__ W,
                               ushort* __restrict__ whi, ushort* __restrict__ wlo) {
    int i = blockIdx.x * 256 + threadIdx.x;
    if (i < C_CH * C_CH) {
        float w = W[i];
        ushort h = f2bf(w);
        whi[i] = h;
        wlo[i] = f2bf(w - bf2f(h));
    }
}

template<bool USE_WS>
__global__ __launch_bounds__(THREADS, 6)
void vn_mfma32(const float* __restrict__ x,
               const float* __restrict__ Wf,
               const ushort* __restrict__ whi, const ushort* __restrict__ wlo,
               float* __restrict__ out) {
    // LDS row = v*64 + i  (i = input channel), packed (hi<<16)|lo. 24 KB.
    __shared__ unsigned xs[V_DIM * C_CH][NT];

    const int t    = threadIdx.x;
    const int tile = blockIdx.x;
    const int b    = tile >> 10;            // 1024 tiles per batch
    const int n0   = (tile & 1023) << 5;    // *32

    const float* xb = x + (size_t)b * (C_CH * V_DIM * N_FULL) + n0;

    const int lane = t & 63;
    const int w    = t >> 6;
    const int wo   = w >> 1;   // o-half -> 32 rows
    const int wn   = w & 1;    // n-half -> 16 cols
    const int l4   = lane & 15;
    const int hi   = lane >> 4;

    // ---- A fragments: Ah/Al[m][kh], row = wo*32+m*16+l4, k = kh*32+hi*8+j
    bf16x8 Ah[2][2], Al[2][2];
    if (USE_WS) {
        #pragma unroll
        for (int m = 0; m < 2; ++m)
            #pragma unroll
            for (int kh = 0; kh < 2; ++kh) {
                size_t off = (size_t)(wo * 32 + m * 16 + l4) * C_CH + kh * 32 + hi * 8;
                Ah[m][kh] = *(const bf16x8*)(whi + off);
                Al[m][kh] = *(const bf16x8*)(wlo + off);
            }
    } else {
        #pragma unroll
        for (int m = 0; m < 2; ++m)
            #pragma unroll
            for (int kh = 0; kh < 2; ++kh) {
                const float* wp = Wf + (size_t)(wo * 32 + m * 16 + l4) * C_CH + kh * 32 + hi * 8;
                float4 wa = *(const float4*)wp;
                float4 wb = *(const float4*)(wp + 4);
                float wf[8] = {wa.x, wa.y, wa.z, wa.w, wb.x, wb.y, wb.z, wb.w};
                bf16x8 h, l;
                #pragma unroll
                for (int j = 0; j < 8; ++j) {
                    ushort hb = f2bf(wf[j]);
                    h[j] = (short)hb;
                    l[j] = (short)f2bf(wf[j] - bf2f(hb));
                }
                Ah[m][kh] = h; Al[m][kh] = l;
            }
    }

    // ---- stage x tile: 192 global rows x 32 f32 -> packed LDS [v*64+i][n]
    // global row r = 3*i + v ; LDS row = v*64 + i ; col ^= ((row>>3)&1)<<4
    #pragma unroll
    for (int it = 0; it < 6; ++it) {
        int idx = t + it * THREADS;      // 0..1535 float4-slots
        int r   = idx >> 3;              // global row 0..191 (8 float4/row)
        int c4  = (idx & 7) << 2;        // dword col base
        int i   = (r * 171) >> 9;        // r / 3 (exact for r < 768)
        int v   = r - 3 * i;
        int rowp = v * 64 + i;
        float4 vf4 = *(const float4*)(xb + (size_t)r * N_FULL + c4);
        float vf[4] = {vf4.x, vf4.y, vf4.z, vf4.w};
        unsigned p[4];
        #pragma unroll
        for (int q = 0; q < 4; ++q) p[q] = pack_hl(vf[q]);
        int col = c4 ^ (((rowp >> 3) & 1) << 4);
        *(uint4*)&xs[rowp][col] = *(const uint4*)p;
    }
    __syncthreads();

    f32x4 acc[2][3];
    #pragma unroll
    for (int m = 0; m < 2; ++m)
        #pragma unroll
        for (int v = 0; v < 3; ++v)
            acc[m][v] = (f32x4){0.f, 0.f, 0.f, 0.f};

    // ---- MFMA: B-frag rows = v*64 + kh*32 + hi*8 + j -> (row>>3)&1 == hi&1
    const int bcol = (wn * 16 + l4) ^ ((hi & 1) << 4);  // hoisted, const/thread
    #pragma unroll
    for (int v = 0; v < 3; ++v) {
        #pragma unroll
        for (int kh = 0; kh < 2; ++kh) {
            unsigned p[8];
            #pragma unroll
            for (int j = 0; j < 8; ++j)
                p[j] = xs[v * 64 + kh * 32 + hi * 8 + j][bcol];
            union { bf16x8 v8; unsigned d[4]; } BH, BL;
            #pragma unroll
            for (int q = 0; q < 4; ++q) {
                BH.d[q] = __builtin_amdgcn_perm(p[2 * q + 1], p[2 * q], 0x07060302u);
                BL.d[q] = __builtin_amdgcn_perm(p[2 * q + 1], p[2 * q], 0x05040100u);
            }
            #pragma unroll
            for (int m = 0; m < 2; ++m) {
                acc[m][v] = __builtin_amdgcn_mfma_f32_16x16x32_bf16(Ah[m][kh], BH.v8, acc[m][v], 0, 0, 0);
                acc[m][v] = __builtin_amdgcn_mfma_f32_16x16x32_bf16(Ah[m][kh], BL.v8, acc[m][v], 0, 0, 0);
                acc[m][v] = __builtin_amdgcn_mfma_f32_16x16x32_bf16(Al[m][kh], BH.v8, acc[m][v], 0, 0, 0);
            }
        }
    }

    // ---- epilogue: C/D col=l4 (n), row=hi*4+r (o within 16)
    // LDS row = v*64 + o, o = wo*32+m*16+hi*4+r -> (row>>3)&1 == hi>>1
    const int n    = wn * 16 + l4;
    const int ecol = n ^ ((hi >> 1) << 4);  // hoisted, const/thread
    float* ob = out + (size_t)b * (C_CH * V_DIM * N_FULL) + n0 + n;
    #pragma unroll
    for (int m = 0; m < 2; ++m) {
        #pragma unroll
        for (int r = 0; r < 4; ++r) {
            const int o = wo * 32 + m * 16 + hi * 4 + r;
            float xv[3], dv[3];
            #pragma unroll
            for (int v = 0; v < 3; ++v) {
                unsigned p = xs[v * 64 + o][ecol];
                xv[v] = u2f(p & 0xffff0000u) + u2f(p << 16);
                dv[v] = acc[m][v][r];
            }
            float dot  = xv[0] * dv[0] + xv[1] * dv[1] + xv[2] * dv[2];
            float dnsq = dv[0] * dv[0] + dv[1] * dv[1] + dv[2] * dv[2];
            float f = (1.0f - NEG_SLOPE) * dot / (dnsq + EPS);
            float o0, o1, o2;
            if (dot >= 0.f) {
                o0 = xv[0]; o1 = xv[1]; o2 = xv[2];
            } else {
                o0 = xv[0] - f * dv[0]; o1 = xv[1] - f * dv[1]; o2 = xv[2] - f * dv[2];
            }
            float* op = ob + (size_t)o * (V_DIM * N_FULL);
            op[0 * N_FULL] = o0;
            op[1 * N_FULL] = o1;
            op[2 * N_FULL] = o2;
        }
    }
}

extern "C" void kernel_launch(void* const* d_in, const int* in_sizes, int n_in,
                              void* d_out, int out_size, void* d_ws, size_t ws_size,
                              hipStream_t stream) {
    const float* x = (const float*)d_in[0];
    const float* W = (const float*)d_in[1];
    float* out = (float*)d_out;

    const int B = 4;
    const int blocks = B * (N_FULL / NT);  // 4096

    if (ws_size >= 2u * C_CH * C_CH * sizeof(ushort)) {
        ushort* whi = (ushort*)d_ws;
        ushort* wlo = whi + C_CH * C_CH;
        w_split_kernel<<<(C_CH * C_CH + 255) / 256, 256, 0, stream>>>(W, whi, wlo);
        vn_mfma32<true><<<blocks, THREADS, 0, stream>>>(x, W, whi, wlo, out);
    } else {
        vn_mfma32<false><<<blocks, THREADS, 0, stream>>>(x, W, nullptr, nullptr, out);
    }
}